// Round 19
// baseline (70.141 us; speedup 1.0000x reference)
//
#include <hip/hip_runtime.h>

// RoIAlign-3D: x[2,256,16,64,64] f32, rois[128,5] -> out[128,256,16,7,7] f32
// R17: R13's 2-deep software-pipelined j-loop, correctly capped this time.
// KEY FIX: __launch_bounds__(512) with NO min-waves arg. R13 used (512,4) =
// 8 waves/SIMD = hard 64-VGPR cap -> the ~90-reg 2-deep pipeline spilled.
// LDS (66.5KB -> 2 blocks/CU = 4 waves/SIMD) is the real occupancy limit, so
// the cap was pure loss. Per iteration: issue 18 ds_read_b128 (slots j, j+1),
// compute j under j+1's reads, prefetch j+2's meta under j+1's compute.
// jtn rounded EVEN (dup-slot pad = benign identical rewrites).

#define PITCHC 65
#define ROWB   (PITCHC * 16)   // 1040 B per texel row

typedef float v2f __attribute__((ext_vector_type(2)));

__global__ __launch_bounds__(256) void pooler_pre(const float* __restrict__ rois,
                                                  int* __restrict__ list,
                                                  int* __restrict__ jt,
                                                  uint4* __restrict__ meta) {
    __shared__ int simg[128];
    __shared__ int sorted[256];
    __shared__ int scnt[2];
    const int tid = threadIdx.x;
    if (tid < 128) simg[tid] = (int)rois[5 * tid];
    __syncthreads();
    if (tid == 0) {
        int c0 = 0, c1 = 0;
        for (int j = 0; j < 128; ++j) {
            if (simg[j] == 0) sorted[c0++] = j;
            else              sorted[128 + c1++] = j;
        }
        scnt[0] = c0; scnt[1] = c1;
        int t0 = (c0 + 7) >> 3, t1 = (c1 + 7) >> 3;
        jt[0] = (t0 + 1) & ~1;             // even trip count for 2-stage pipe
        jt[1] = (t1 + 1) & ~1;
    }
    __syncthreads();
    const int img = tid >> 7, idx = tid & 127;
    const int cnt = scnt[img];
    int k = 0;
    if (cnt > 0) k = (idx < cnt) ? sorted[(img << 7) + idx] : sorted[img << 7];
    list[tid] = k;   // pad slots duplicate the image's first ROI (identical rewrites)

    float x1 = rois[5*k+1]*0.25f, y1 = rois[5*k+2]*0.25f;
    float x2 = rois[5*k+3]*0.25f, y2 = rois[5*k+4]*0.25f;
    float bw = fmaxf(x2 - x1, 1.0f) * (1.0f / 14.0f);
    float bh = fmaxf(y2 - y1, 1.0f) * (1.0f / 14.0f);
    for (int i = 0; i < 7; ++i) {
        {   // ---- y: 2 samples -> 3-row weights (mask folded); clamp+shift
            float s0 = fmaf((float)(2*i) + 0.5f, bh, y1), s1 = s0 + bh;
            float m0 = (s0 >= -1.f && s0 <= 64.f) ? 1.f : 0.f;
            float m1 = (s1 >= -1.f && s1 <= 64.f) ? 1.f : 0.f;
            float c0 = fminf(fmaxf(s0, 0.f), 63.f), c1 = fminf(fmaxf(s1, 0.f), 63.f);
            int i0 = min((int)c0, 62), i1 = min((int)c1, 62);
            float l0 = c0 - (float)i0, l1 = c1 - (float)i1;
            float h0 = (1.f - l0) * m0, L0 = l0 * m0;
            float h1 = (1.f - l1) * m1, L1 = l1 * m1;
            bool d = (i1 != i0);
            float w0 = h0 + (d ? 0.f : h1);
            float w1 = L0 + (d ? h1 : L1);
            float w2 = d ? L1 : 0.f;
            int b = i0;
            if (i0 > 61) { b = 61; w2 = w1; w1 = w0; w0 = 0.f; }
            uint4 e;
            e.x = __float_as_uint(w0); e.y = __float_as_uint(w1);
            e.z = __float_as_uint(w2); e.w = (unsigned)b;      // texel row
            meta[tid * 14 + i] = e;
        }
        {   // ---- x: same, 1/4 sample-mean folded
            float s0 = fmaf((float)(2*i) + 0.5f, bw, x1), s1 = s0 + bw;
            float m0 = (s0 >= -1.f && s0 <= 64.f) ? 0.25f : 0.f;
            float m1 = (s1 >= -1.f && s1 <= 64.f) ? 0.25f : 0.f;
            float c0 = fminf(fmaxf(s0, 0.f), 63.f), c1 = fminf(fmaxf(s1, 0.f), 63.f);
            int i0 = min((int)c0, 62), i1 = min((int)c1, 62);
            float l0 = c0 - (float)i0, l1 = c1 - (float)i1;
            float h0 = (1.f - l0) * m0, L0 = l0 * m0;
            float h1 = (1.f - l1) * m1, L1 = l1 * m1;
            bool d = (i1 != i0);
            float w0 = h0 + (d ? 0.f : h1);
            float w1 = L0 + (d ? h1 : L1);
            float w2 = d ? L1 : 0.f;
            int b = i0;
            if (i0 > 61) { b = 61; w2 = w1; w1 = w0; w0 = 0.f; }
            uint4 e;
            e.x = __float_as_uint(w0); e.y = __float_as_uint(w1);
            e.z = __float_as_uint(w2); e.w = (unsigned)b;      // texel col
            meta[tid * 14 + 7 + i] = e;
        }
    }
}

// bf16 pack (round-to-nearest-even) / unpack via bit ops.
__device__ __forceinline__ unsigned bfrne(float f) {
    unsigned u = __float_as_uint(f);
    return (u + 0x7FFFu + ((u >> 16) & 1u)) >> 16;
}
__device__ __forceinline__ unsigned pack2(float lo, float hi) {
    return bfrne(lo) | (bfrne(hi) << 16);
}
__device__ __forceinline__ v2f up2(unsigned q) {   // (lo, hi) bf16 pair -> v2f
    return v2f{__uint_as_float(q << 16), __uint_as_float(q & 0xFFFF0000u)};
}

struct Q9 { uint4 a, b, c, d, e, f, g, h, i; };

__device__ __forceinline__ Q9 loadQ(const char* lds, uint4 ye, uint4 xe) {
    const char* p0 = lds + (int)ye.w * ROWB + ((int)xe.w << 4);
    Q9 q;
    q.a = *(const uint4*)(p0);
    q.b = *(const uint4*)(p0 + 16);
    q.c = *(const uint4*)(p0 + 32);
    q.d = *(const uint4*)(p0 + ROWB);
    q.e = *(const uint4*)(p0 + ROWB + 16);
    q.f = *(const uint4*)(p0 + ROWB + 32);
    q.g = *(const uint4*)(p0 + 2 * ROWB);
    q.h = *(const uint4*)(p0 + 2 * ROWB + 16);
    q.i = *(const uint4*)(p0 + 2 * ROWB + 32);
    return q;
}

__device__ __forceinline__ void computeStore(const Q9& q, uint4 ye, uint4 xe,
                                             int kk, float* obase, bool act) {
    float yw0 = __uint_as_float(ye.x);
    float yw1 = __uint_as_float(ye.y);
    float yw2 = __uint_as_float(ye.z);
    float xw0 = __uint_as_float(xe.x);
    float xw1 = __uint_as_float(xe.y);
    float xw2 = __uint_as_float(xe.z);
    float w00 = yw0*xw0, w01 = yw0*xw1, w02 = yw0*xw2;
    float w10 = yw1*xw0, w11 = yw1*xw1, w12 = yw1*xw2;
    float w20 = yw2*xw0, w21 = yw2*xw1, w22 = yw2*xw2;

    v2f acc0, acc1, acc2, acc3, W;
    W = v2f{w00, w00};
    acc0 = up2(q.a.x) * W; acc1 = up2(q.a.y) * W;
    acc2 = up2(q.a.z) * W; acc3 = up2(q.a.w) * W;
    W = v2f{w01, w01};
    acc0 = __builtin_elementwise_fma(up2(q.b.x), W, acc0);
    acc1 = __builtin_elementwise_fma(up2(q.b.y), W, acc1);
    acc2 = __builtin_elementwise_fma(up2(q.b.z), W, acc2);
    acc3 = __builtin_elementwise_fma(up2(q.b.w), W, acc3);
    W = v2f{w02, w02};
    acc0 = __builtin_elementwise_fma(up2(q.c.x), W, acc0);
    acc1 = __builtin_elementwise_fma(up2(q.c.y), W, acc1);
    acc2 = __builtin_elementwise_fma(up2(q.c.z), W, acc2);
    acc3 = __builtin_elementwise_fma(up2(q.c.w), W, acc3);
    W = v2f{w10, w10};
    acc0 = __builtin_elementwise_fma(up2(q.d.x), W, acc0);
    acc1 = __builtin_elementwise_fma(up2(q.d.y), W, acc1);
    acc2 = __builtin_elementwise_fma(up2(q.d.z), W, acc2);
    acc3 = __builtin_elementwise_fma(up2(q.d.w), W, acc3);
    W = v2f{w11, w11};
    acc0 = __builtin_elementwise_fma(up2(q.e.x), W, acc0);
    acc1 = __builtin_elementwise_fma(up2(q.e.y), W, acc1);
    acc2 = __builtin_elementwise_fma(up2(q.e.z), W, acc2);
    acc3 = __builtin_elementwise_fma(up2(q.e.w), W, acc3);
    W = v2f{w12, w12};
    acc0 = __builtin_elementwise_fma(up2(q.f.x), W, acc0);
    acc1 = __builtin_elementwise_fma(up2(q.f.y), W, acc1);
    acc2 = __builtin_elementwise_fma(up2(q.f.z), W, acc2);
    acc3 = __builtin_elementwise_fma(up2(q.f.w), W, acc3);
    W = v2f{w20, w20};
    acc0 = __builtin_elementwise_fma(up2(q.g.x), W, acc0);
    acc1 = __builtin_elementwise_fma(up2(q.g.y), W, acc1);
    acc2 = __builtin_elementwise_fma(up2(q.g.z), W, acc2);
    acc3 = __builtin_elementwise_fma(up2(q.g.w), W, acc3);
    W = v2f{w21, w21};
    acc0 = __builtin_elementwise_fma(up2(q.h.x), W, acc0);
    acc1 = __builtin_elementwise_fma(up2(q.h.y), W, acc1);
    acc2 = __builtin_elementwise_fma(up2(q.h.z), W, acc2);
    acc3 = __builtin_elementwise_fma(up2(q.h.w), W, acc3);
    W = v2f{w22, w22};
    acc0 = __builtin_elementwise_fma(up2(q.i.x), W, acc0);
    acc1 = __builtin_elementwise_fma(up2(q.i.y), W, acc1);
    acc2 = __builtin_elementwise_fma(up2(q.i.z), W, acc2);
    acc3 = __builtin_elementwise_fma(up2(q.i.w), W, acc3);

    if (act) {
        float* po = obase + (size_t)kk * 200704;
        po[0]   = acc0.x;
        po[49]  = acc0.y;
        po[98]  = acc1.x;
        po[147] = acc1.y;
        po[196] = acc2.x;
        po[245] = acc2.y;
        po[294] = acc3.x;
        po[343] = acc3.y;
    }
}

__global__ __launch_bounds__(512) void pooler_main(const float* __restrict__ x,
                                                   const int* __restrict__ list,
                                                   const int* __restrict__ jt,
                                                   const uint4* __restrict__ meta,
                                                   float* __restrict__ out) {
    __shared__ __align__(16) char lds[64 * ROWB];   // 66,560 B -> 2 blocks/CU

    const int tid = threadIdx.x;
    const int bid = blockIdx.x;
    const int h   = bid & 1;                // t-half
    const int c   = (bid >> 1) & 255;
    const int img = bid >> 9;
    const int sbase = img << 7;
    const int jtn = jt[img];

    const int lane = tid & 63, wave = tid >> 6;
    const int o  = lane;
    const int oc = o < 49 ? o : 48;
    const int ph = oc / 7, pw = oc - ph * 7;

    // ---- stage this half's 8 planes as bf16 chunks (texel-major, pitch 65)
    const float* gb = x + ((size_t)((((img << 8) + c) << 4) + (h << 3)) << 12);
    #pragma unroll
    for (int g = 0; g < 2; ++g) {
        int q = tid + (g << 9);             // quad 0..1023 -> texels 4q..4q+3
        const float4* gq = (const float4*)gb + q;
        float4 v0 = gq[0];
        float4 v1 = gq[1024];
        float4 v2 = gq[2048];
        float4 v3 = gq[3072];
        float4 v4 = gq[4096];
        float4 v5 = gq[5120];
        float4 v6 = gq[6144];
        float4 v7 = gq[7168];
        float a0[4] = {v0.x, v0.y, v0.z, v0.w};
        float a1[4] = {v1.x, v1.y, v1.z, v1.w};
        float a2[4] = {v2.x, v2.y, v2.z, v2.w};
        float a3[4] = {v3.x, v3.y, v3.z, v3.w};
        float a4[4] = {v4.x, v4.y, v4.z, v4.w};
        float a5[4] = {v5.x, v5.y, v5.z, v5.w};
        float a6[4] = {v6.x, v6.y, v6.z, v6.w};
        float a7[4] = {v7.x, v7.y, v7.z, v7.w};
        int y = q >> 4, xb4 = (q & 15) << 2;
        char* d = lds + y * ROWB + (xb4 << 4);
        #pragma unroll
        for (int e = 0; e < 4; ++e) {
            uint4 ch;
            ch.x = pack2(a0[e], a1[e]);
            ch.y = pack2(a2[e], a3[e]);
            ch.z = pack2(a4[e], a5[e]);
            ch.w = pack2(a6[e], a7[e]);
            *(uint4*)(d + (e << 4)) = ch;
        }
    }
    __syncthreads();

    if (jtn > 0) {
        float* obase = out + (size_t)c * 784 + ((h << 3) * 49) + o;
        const int base = sbase + wave;
        const bool act = (o < 49);
        int sA = base;
        int kA = list[sA];
        uint4 yeA = meta[sA * 14 + ph];
        uint4 xeA = meta[sA * 14 + 7 + pw];
        for (int j = 0; j < jtn; j += 2) {
            int sB = base + ((j + 1) << 3);
            int kB = list[sB];
            uint4 yeB = meta[sB * 14 + ph];
            uint4 xeB = meta[sB * 14 + 7 + pw];
            Q9 qA = loadQ(lds, yeA, xeA);        // issue A's 9 reads
            Q9 qB = loadQ(lds, yeB, xeB);        // issue B's 9 reads (in flight under A)
            computeStore(qA, yeA, xeA, kA, obase, act);
            int jn = (j + 2 < jtn) ? j + 2 : jtn - 1;   // prefetch next A meta
            int sN = base + (jn << 3);
            kA  = list[sN];
            yeA = meta[sN * 14 + ph];
            xeA = meta[sN * 14 + 7 + pw];
            computeStore(qB, yeB, xeB, kB, obase, act);
        }
    }
}

extern "C" void kernel_launch(void* const* d_in, const int* in_sizes, int n_in,
                              void* d_out, int out_size, void* d_ws, size_t ws_size,
                              hipStream_t stream) {
    const float* x    = (const float*)d_in[0];
    const float* rois = (const float*)d_in[1];
    float* out = (float*)d_out;
    int*   list = (int*)d_ws;
    int*   jtp  = (int*)((char*)d_ws + 1024);
    uint4* meta = (uint4*)((char*)d_ws + 2048);
    pooler_pre<<<1, 256, 0, stream>>>(rois, list, jtp, meta);
    pooler_main<<<1024, 512, 0, stream>>>(x, list, jtp, meta, out);
}

// Round 20
// 59.335 us; speedup vs baseline: 1.1821x; 1.1821x over previous
//
#include <hip/hip_runtime.h>

// RoIAlign-3D: x[2,256,16,64,64] f32, rois[128,5] -> out[128,256,16,7,7] f32
// FINAL = R11 (best verified: 59.0us wall). Block = (img, c, t-half); stages
// its 8 planes exactly once as bf16 16B 8-plane chunks ([64][65] texel-major,
// 66.5KB LDS -> 2 blocks/CU, stage/compute overlap via co-residency). Wave =
// ROI-slot chain (slots wave+8j, dup-k padded uniform jtn, next-j meta
// prefetch): per j, 9 ds_read_b128 -> 8 outputs/lane, ~20 VALU (v2f packed
// FMA), 1568B/wave write bursts (no partial-line RMW at this residency).
// Lessons encoded: no launch-bounds min-arg below natural VGPR (spill),
// no per-thread ILP pipelining (occupancy loss > latency gain), TLP beyond
// 16 waves/CU null, XCD swizzle null. f32 weights; bf16 texels (bit-ops).

#define PITCHC 65
#define ROWB   (PITCHC * 16)   // 1040 B per texel row

typedef float v2f __attribute__((ext_vector_type(2)));

__global__ __launch_bounds__(256) void pooler_pre(const float* __restrict__ rois,
                                                  int* __restrict__ list,
                                                  int* __restrict__ jt,
                                                  uint4* __restrict__ meta) {
    __shared__ int simg[128];
    __shared__ int sorted[256];
    __shared__ int scnt[2];
    const int tid = threadIdx.x;
    if (tid < 128) simg[tid] = (int)rois[5 * tid];
    __syncthreads();
    if (tid == 0) {
        int c0 = 0, c1 = 0;
        for (int j = 0; j < 128; ++j) {
            if (simg[j] == 0) sorted[c0++] = j;
            else              sorted[128 + c1++] = j;
        }
        scnt[0] = c0; scnt[1] = c1;
        jt[0] = (c0 + 7) >> 3;
        jt[1] = (c1 + 7) >> 3;
    }
    __syncthreads();
    const int img = tid >> 7, idx = tid & 127;
    const int cnt = scnt[img];
    int k = 0;
    if (cnt > 0) k = (idx < cnt) ? sorted[(img << 7) + idx] : sorted[img << 7];
    list[tid] = k;   // pad slots duplicate the image's first ROI (identical rewrites)

    float x1 = rois[5*k+1]*0.25f, y1 = rois[5*k+2]*0.25f;
    float x2 = rois[5*k+3]*0.25f, y2 = rois[5*k+4]*0.25f;
    float bw = fmaxf(x2 - x1, 1.0f) * (1.0f / 14.0f);
    float bh = fmaxf(y2 - y1, 1.0f) * (1.0f / 14.0f);
    for (int i = 0; i < 7; ++i) {
        {   // ---- y: 2 samples -> 3-row weights (mask folded); clamp+shift
            float s0 = fmaf((float)(2*i) + 0.5f, bh, y1), s1 = s0 + bh;
            float m0 = (s0 >= -1.f && s0 <= 64.f) ? 1.f : 0.f;
            float m1 = (s1 >= -1.f && s1 <= 64.f) ? 1.f : 0.f;
            float c0 = fminf(fmaxf(s0, 0.f), 63.f), c1 = fminf(fmaxf(s1, 0.f), 63.f);
            int i0 = min((int)c0, 62), i1 = min((int)c1, 62);
            float l0 = c0 - (float)i0, l1 = c1 - (float)i1;
            float h0 = (1.f - l0) * m0, L0 = l0 * m0;
            float h1 = (1.f - l1) * m1, L1 = l1 * m1;
            bool d = (i1 != i0);
            float w0 = h0 + (d ? 0.f : h1);
            float w1 = L0 + (d ? h1 : L1);
            float w2 = d ? L1 : 0.f;
            int b = i0;
            if (i0 > 61) { b = 61; w2 = w1; w1 = w0; w0 = 0.f; }
            uint4 e;
            e.x = __float_as_uint(w0); e.y = __float_as_uint(w1);
            e.z = __float_as_uint(w2); e.w = (unsigned)b;      // texel row
            meta[tid * 14 + i] = e;
        }
        {   // ---- x: same, 1/4 sample-mean folded
            float s0 = fmaf((float)(2*i) + 0.5f, bw, x1), s1 = s0 + bw;
            float m0 = (s0 >= -1.f && s0 <= 64.f) ? 0.25f : 0.f;
            float m1 = (s1 >= -1.f && s1 <= 64.f) ? 0.25f : 0.f;
            float c0 = fminf(fmaxf(s0, 0.f), 63.f), c1 = fminf(fmaxf(s1, 0.f), 63.f);
            int i0 = min((int)c0, 62), i1 = min((int)c1, 62);
            float l0 = c0 - (float)i0, l1 = c1 - (float)i1;
            float h0 = (1.f - l0) * m0, L0 = l0 * m0;
            float h1 = (1.f - l1) * m1, L1 = l1 * m1;
            bool d = (i1 != i0);
            float w0 = h0 + (d ? 0.f : h1);
            float w1 = L0 + (d ? h1 : L1);
            float w2 = d ? L1 : 0.f;
            int b = i0;
            if (i0 > 61) { b = 61; w2 = w1; w1 = w0; w0 = 0.f; }
            uint4 e;
            e.x = __float_as_uint(w0); e.y = __float_as_uint(w1);
            e.z = __float_as_uint(w2); e.w = (unsigned)b;      // texel col
            meta[tid * 14 + 7 + i] = e;
        }
    }
}

// bf16 pack (round-to-nearest-even) / unpack via bit ops.
__device__ __forceinline__ unsigned bfrne(float f) {
    unsigned u = __float_as_uint(f);
    return (u + 0x7FFFu + ((u >> 16) & 1u)) >> 16;
}
__device__ __forceinline__ unsigned pack2(float lo, float hi) {
    return bfrne(lo) | (bfrne(hi) << 16);
}
__device__ __forceinline__ v2f up2(unsigned q) {   // (lo, hi) bf16 pair -> v2f
    return v2f{__uint_as_float(q << 16), __uint_as_float(q & 0xFFFF0000u)};
}

__global__ __launch_bounds__(512, 4) void pooler_main(const float* __restrict__ x,
                                                      const int* __restrict__ list,
                                                      const int* __restrict__ jt,
                                                      const uint4* __restrict__ meta,
                                                      float* __restrict__ out) {
    __shared__ __align__(16) char lds[64 * ROWB];   // 66,560 B -> 2 blocks/CU

    const int tid = threadIdx.x;
    const int bid = blockIdx.x;
    const int h   = bid & 1;                // t-half
    const int c   = (bid >> 1) & 255;
    const int img = bid >> 9;
    const int sbase = img << 7;
    const int jtn = jt[img];

    const int lane = tid & 63, wave = tid >> 6;
    const int o  = lane;
    const int oc = o < 49 ? o : 48;
    const int ph = oc / 7, pw = oc - ph * 7;

    // ---- stage this half's 8 planes as bf16 chunks (texel-major, pitch 65)
    const float* gb = x + ((size_t)((((img << 8) + c) << 4) + (h << 3)) << 12);
    #pragma unroll
    for (int g = 0; g < 2; ++g) {
        int q = tid + (g << 9);             // quad 0..1023 -> texels 4q..4q+3
        const float4* gq = (const float4*)gb + q;
        float4 v0 = gq[0];
        float4 v1 = gq[1024];
        float4 v2 = gq[2048];
        float4 v3 = gq[3072];
        float4 v4 = gq[4096];
        float4 v5 = gq[5120];
        float4 v6 = gq[6144];
        float4 v7 = gq[7168];
        float a0[4] = {v0.x, v0.y, v0.z, v0.w};
        float a1[4] = {v1.x, v1.y, v1.z, v1.w};
        float a2[4] = {v2.x, v2.y, v2.z, v2.w};
        float a3[4] = {v3.x, v3.y, v3.z, v3.w};
        float a4[4] = {v4.x, v4.y, v4.z, v4.w};
        float a5[4] = {v5.x, v5.y, v5.z, v5.w};
        float a6[4] = {v6.x, v6.y, v6.z, v6.w};
        float a7[4] = {v7.x, v7.y, v7.z, v7.w};
        int y = q >> 4, xb4 = (q & 15) << 2;
        char* d = lds + y * ROWB + (xb4 << 4);
        #pragma unroll
        for (int e = 0; e < 4; ++e) {
            uint4 ch;
            ch.x = pack2(a0[e], a1[e]);
            ch.y = pack2(a2[e], a3[e]);
            ch.z = pack2(a4[e], a5[e]);
            ch.w = pack2(a6[e], a7[e]);
            *(uint4*)(d + (e << 4)) = ch;
        }
    }
    __syncthreads();

    if (jtn > 0) {
        int s0 = sbase + wave;
        int k0 = list[s0];
        uint4 ye0 = meta[s0 * 14 + ph];
        uint4 xe0 = meta[s0 * 14 + 7 + pw];
        for (int j = 0; j < jtn; ++j) {
            int sn = sbase + wave + (min(j + 1, jtn - 1) << 3);
            int k1 = list[sn];                      // prefetch next slot's meta
            uint4 ye1 = meta[sn * 14 + ph];
            uint4 xe1 = meta[sn * 14 + 7 + pw];

            float yw0 = __uint_as_float(ye0.x);
            float yw1 = __uint_as_float(ye0.y);
            float yw2 = __uint_as_float(ye0.z);
            float xw0 = __uint_as_float(xe0.x);
            float xw1 = __uint_as_float(xe0.y);
            float xw2 = __uint_as_float(xe0.z);
            int yb = (int)ye0.w, xb = (int)xe0.w;

            const char* p0 = lds + yb * ROWB + (xb << 4);
            float w00 = yw0*xw0, w01 = yw0*xw1, w02 = yw0*xw2;
            float w10 = yw1*xw0, w11 = yw1*xw1, w12 = yw1*xw2;
            float w20 = yw2*xw0, w21 = yw2*xw1, w22 = yw2*xw2;

            uint4 q00 = *(const uint4*)(p0);
            uint4 q01 = *(const uint4*)(p0 + 16);
            uint4 q02 = *(const uint4*)(p0 + 32);
            uint4 q10 = *(const uint4*)(p0 + ROWB);
            uint4 q11 = *(const uint4*)(p0 + ROWB + 16);
            uint4 q12 = *(const uint4*)(p0 + ROWB + 32);
            uint4 q20 = *(const uint4*)(p0 + 2 * ROWB);
            uint4 q21 = *(const uint4*)(p0 + 2 * ROWB + 16);
            uint4 q22 = *(const uint4*)(p0 + 2 * ROWB + 32);

            v2f acc0, acc1, acc2, acc3, W;
            W = v2f{w00, w00};
            acc0 = up2(q00.x) * W; acc1 = up2(q00.y) * W;
            acc2 = up2(q00.z) * W; acc3 = up2(q00.w) * W;
            W = v2f{w01, w01};
            acc0 = __builtin_elementwise_fma(up2(q01.x), W, acc0);
            acc1 = __builtin_elementwise_fma(up2(q01.y), W, acc1);
            acc2 = __builtin_elementwise_fma(up2(q01.z), W, acc2);
            acc3 = __builtin_elementwise_fma(up2(q01.w), W, acc3);
            W = v2f{w02, w02};
            acc0 = __builtin_elementwise_fma(up2(q02.x), W, acc0);
            acc1 = __builtin_elementwise_fma(up2(q02.y), W, acc1);
            acc2 = __builtin_elementwise_fma(up2(q02.z), W, acc2);
            acc3 = __builtin_elementwise_fma(up2(q02.w), W, acc3);
            W = v2f{w10, w10};
            acc0 = __builtin_elementwise_fma(up2(q10.x), W, acc0);
            acc1 = __builtin_elementwise_fma(up2(q10.y), W, acc1);
            acc2 = __builtin_elementwise_fma(up2(q10.z), W, acc2);
            acc3 = __builtin_elementwise_fma(up2(q10.w), W, acc3);
            W = v2f{w11, w11};
            acc0 = __builtin_elementwise_fma(up2(q11.x), W, acc0);
            acc1 = __builtin_elementwise_fma(up2(q11.y), W, acc1);
            acc2 = __builtin_elementwise_fma(up2(q11.z), W, acc2);
            acc3 = __builtin_elementwise_fma(up2(q11.w), W, acc3);
            W = v2f{w12, w12};
            acc0 = __builtin_elementwise_fma(up2(q12.x), W, acc0);
            acc1 = __builtin_elementwise_fma(up2(q12.y), W, acc1);
            acc2 = __builtin_elementwise_fma(up2(q12.z), W, acc2);
            acc3 = __builtin_elementwise_fma(up2(q12.w), W, acc3);
            W = v2f{w20, w20};
            acc0 = __builtin_elementwise_fma(up2(q20.x), W, acc0);
            acc1 = __builtin_elementwise_fma(up2(q20.y), W, acc1);
            acc2 = __builtin_elementwise_fma(up2(q20.z), W, acc2);
            acc3 = __builtin_elementwise_fma(up2(q20.w), W, acc3);
            W = v2f{w21, w21};
            acc0 = __builtin_elementwise_fma(up2(q21.x), W, acc0);
            acc1 = __builtin_elementwise_fma(up2(q21.y), W, acc1);
            acc2 = __builtin_elementwise_fma(up2(q21.z), W, acc2);
            acc3 = __builtin_elementwise_fma(up2(q21.w), W, acc3);
            W = v2f{w22, w22};
            acc0 = __builtin_elementwise_fma(up2(q22.x), W, acc0);
            acc1 = __builtin_elementwise_fma(up2(q22.y), W, acc1);
            acc2 = __builtin_elementwise_fma(up2(q22.z), W, acc2);
            acc3 = __builtin_elementwise_fma(up2(q22.w), W, acc3);

            if (o < 49) {
                float* po = out + (size_t)k0 * 200704 + (size_t)c * 784 + (h << 3) * 49 + o;
                po[0]   = acc0.x;
                po[49]  = acc0.y;
                po[98]  = acc1.x;
                po[147] = acc1.y;
                po[196] = acc2.x;
                po[245] = acc2.y;
                po[294] = acc3.x;
                po[343] = acc3.y;
            }
            k0 = k1; ye0 = ye1; xe0 = xe1;
        }
    }
}

extern "C" void kernel_launch(void* const* d_in, const int* in_sizes, int n_in,
                              void* d_out, int out_size, void* d_ws, size_t ws_size,
                              hipStream_t stream) {
    const float* x    = (const float*)d_in[0];
    const float* rois = (const float*)d_in[1];
    float* out = (float*)d_out;
    int*   list = (int*)d_ws;
    int*   jtp  = (int*)((char*)d_ws + 1024);
    uint4* meta = (uint4*)((char*)d_ws + 2048);
    pooler_pre<<<1, 256, 0, stream>>>(rois, list, jtp, meta);
    pooler_main<<<1024, 512, 0, stream>>>(x, list, jtp, meta, out);
}